// Round 2
// baseline (599.119 us; speedup 1.0000x reference)
//
#include <hip/hip_runtime.h>
#include <cmath>

typedef unsigned long long u64;
typedef __attribute__((ext_vector_type(2))) unsigned long long u64x2;

constexpr int      kLevels         = 12;
constexpr unsigned kHashSize       = 1u << 19;           // 524288 entries per level
constexpr unsigned kHashMask       = kHashSize - 1u;
constexpr int      kPoints         = 1 << 21;            // 2,097,152
constexpr int      kBlock          = 256;
constexpr int      kILP            = 4;
constexpr int      kPtsPerBlk      = kBlock * kILP;      // 1024
constexpr int      kChunksPerLevel = kPoints / kPtsPerBlk;        // 2048
constexpr int      kGatherBlocks   = kLevels * kChunksPerLevel;   // 24576
constexpr int      kXcds           = 8;
constexpr int      kQueueLen       = kGatherBlocks / kXcds;       // 3072

struct ResArr { float r[kLevels]; };

// ---------------- Kernel 1: XCD-pinned, level-phased gather -> ws[l][n] ----
// Schedule: blockIdx % 8 selects the XCD (round-robin dispatch heuristic);
// each XCD's queue is level-major, so at any moment an XCD gathers from ONE
// 4 MB table, which exactly fits its private 4 MB L2.
__global__ __launch_bounds__(kBlock) void gather_kernel(
    const float* __restrict__ x,     // [N,3] f32
    const u64*   __restrict__ emb,   // [L * 2^19] entries of 8 B (float2)
    u64*         __restrict__ ws,    // [L][N] of 8 B
    ResArr res)
{
    const unsigned b     = blockIdx.x;
    const unsigned xcd   = b % (unsigned)kXcds;
    const unsigned pos   = b / (unsigned)kXcds;
    const unsigned g     = xcd * (unsigned)kQueueLen + pos;   // level-major item
    const unsigned level = g / (unsigned)kChunksPerLevel;
    const unsigned chunk = g % (unsigned)kChunksPerLevel;

    // wave-uniform level -> resolution (cheap select chain, once per thread)
    float r = res.r[0];
#pragma unroll
    for (int i = 1; i < kLevels; ++i) r = (level == (unsigned)i) ? res.r[i] : r;

    const u64* __restrict__ tab = emb + (size_t)level * kHashSize;
    u64*       __restrict__ wsl = ws  + (size_t)level * kPoints;
    const unsigned base = chunk * (unsigned)kPtsPerBlk + threadIdx.x;

#pragma unroll
    for (int k = 0; k < kILP; ++k) {
        const unsigned p = base + (unsigned)(k * kBlock);
        const float px = x[p * 3u + 0u];
        const float py = x[p * 3u + 1u];
        const float pz = x[p * 3u + 2u];
        // exact IEEE f32 mul + floor, identical to the reference
        const unsigned x0 = (unsigned)floorf(px * r);
        const unsigned y0 = (unsigned)floorf(py * r);
        const unsigned z0 = (unsigned)floorf(pz * r);
        const unsigned h  = (x0 ^ (y0 * 2654435761u) ^ (z0 * 805459861u)) & kHashMask;
        const u64 e = tab[h];                          // L2-resident gather
        __builtin_nontemporal_store(e, wsl + p);       // coalesced stream out
    }
}

// ---------------- Kernel 2: transpose ws[l][n] -> out[n][l] ----------------
__global__ __launch_bounds__(kBlock) void transpose_kernel(
    const u64* __restrict__ ws,      // [L][N]
    u64x2*     __restrict__ out)     // [N*6] x 16 B  (== [N,24] f32)
{
    const unsigned n = blockIdx.x * (unsigned)kBlock + threadIdx.x;
    u64 v[kLevels];
#pragma unroll
    for (int l = 0; l < kLevels; ++l)
        v[l] = __builtin_nontemporal_load(ws + (size_t)l * kPoints + n);
#pragma unroll
    for (int j = 0; j < 6; ++j) {
        u64x2 o;
        o.x = v[2 * j];
        o.y = v[2 * j + 1];
        __builtin_nontemporal_store(o, out + (size_t)n * 6u + j);
    }
}

// ---------------- Fallback (round-1 direct kernel) if ws is too small ------
__global__ __launch_bounds__(kBlock) void direct_kernel(
    const float* __restrict__ x,
    const u64*   __restrict__ emb,
    u64*         __restrict__ out,
    ResArr res)
{
    unsigned tid = blockIdx.x * (unsigned)kBlock + threadIdx.x;  // tid = n*12+l
    unsigned n   = tid / (unsigned)kLevels;
    unsigned l   = tid - n * (unsigned)kLevels;
    float r = res.r[0];
#pragma unroll
    for (int i = 1; i < kLevels; ++i) r = (l == (unsigned)i) ? res.r[i] : r;
    float px = x[n * 3u + 0u], py = x[n * 3u + 1u], pz = x[n * 3u + 2u];
    unsigned x0 = (unsigned)floorf(px * r);
    unsigned y0 = (unsigned)floorf(py * r);
    unsigned z0 = (unsigned)floorf(pz * r);
    unsigned h  = (x0 ^ (y0 * 2654435761u) ^ (z0 * 805459861u)) & kHashMask;
    __builtin_nontemporal_store(emb[l * kHashSize + h], out + tid);
}

extern "C" void kernel_launch(void* const* d_in, const int* in_sizes, int n_in,
                              void* d_out, int out_size, void* d_ws, size_t ws_size,
                              hipStream_t stream) {
    const float* x   = (const float*)d_in[0];
    const u64*   emb = (const u64*)d_in[1];

    // Replicate the reference's float64 resolution computation exactly.
    ResArr res;
    const double growth = std::exp((std::log(512.0) - std::log(16.0)) / 11.0);
    for (int i = 0; i < kLevels; ++i)
        res.r[i] = (float)(int)(16.0 * std::pow(growth, (double)i));

    const size_t ws_needed = (size_t)kLevels * kPoints * sizeof(u64); // 201 MB

    if (ws_size >= ws_needed) {
        hipLaunchKernelGGL(gather_kernel, dim3(kGatherBlocks), dim3(kBlock), 0, stream,
                           x, emb, (u64*)d_ws, res);
        hipLaunchKernelGGL(transpose_kernel, dim3(kPoints / kBlock), dim3(kBlock), 0, stream,
                           (const u64*)d_ws, (u64x2*)d_out);
    } else {
        const int total = kPoints * kLevels;
        hipLaunchKernelGGL(direct_kernel, dim3(total / kBlock), dim3(kBlock), 0, stream,
                           x, emb, (u64*)d_out, res);
    }
}

// Round 3
// 221.023 us; speedup vs baseline: 2.7107x; 2.7107x over previous
//
#include <hip/hip_runtime.h>
#include <cmath>

typedef unsigned long long u64;
typedef __attribute__((ext_vector_type(2))) unsigned long long u64x2;

constexpr int      kLevels   = 12;
constexpr unsigned kHashSize = 1u << 19;            // 524288 entries/level
constexpr unsigned kHashMask = kHashSize - 1u;
constexpr int      kPoints   = 1 << 21;             // 2,097,152
constexpr int      kBlock    = 256;

// Levels 0..2 have small cache-line footprints (~2.2 MB total) -> gathered
// directly in the assemble pass (L2-resident on every XCD). Levels 3..11
// (~2.7-4 MB each) get the XCD-pinned, level-phased gather.
constexpr int kLowLevels = 3;
constexpr int kHiLevels  = kLevels - kLowLevels;    // 9 (levels 3..11)

// ---- pass-1 geometry ----
constexpr int kILP       = 8;
constexpr int kPtsPerBlk = kBlock * kILP;           // 2048
constexpr int kChunks    = kPoints / kPtsPerBlk;    // 1024 chunks/level
constexpr int kGBlocks   = kHiLevels * kChunks;     // 9216
constexpr int kXcds      = 8;
constexpr int kQLen      = kGBlocks / kXcds;        // 1152 (exact)

struct ResArr { float r[kLevels]; };

// ---------- Pass 1: XCD-pinned level-phased gather, levels 3..11 -> ws ----
// blockIdx % 8 picks the XCD (round-robin dispatch); each XCD walks a
// level-major queue so it gathers from 1-2 tables at a time (fits 4 MB L2).
__global__ __launch_bounds__(kBlock) void gather_hi_kernel(
    const float* __restrict__ x,     // [N,3]
    const u64*   __restrict__ emb,   // [L * 2^19] float2 as u64
    u64*         __restrict__ ws,    // [9][N]
    ResArr res)
{
    const unsigned b     = blockIdx.x;
    const unsigned g     = (b % (unsigned)kXcds) * (unsigned)kQLen
                         + (b / (unsigned)kXcds);
    const unsigned li    = g / (unsigned)kChunks;           // 0..8
    const unsigned chunk = g - li * (unsigned)kChunks;
    const unsigned level = li + (unsigned)kLowLevels;

    float r = res.r[kLowLevels];
#pragma unroll
    for (int i = 1; i < kHiLevels; ++i)
        r = (li == (unsigned)i) ? res.r[kLowLevels + i] : r;

    const u64* __restrict__ tab = emb + (size_t)level * kHashSize;
    u64*       __restrict__ wsl = ws  + (size_t)li * kPoints;
    const unsigned base = chunk * (unsigned)kPtsPerBlk + threadIdx.x;

#pragma unroll
    for (int k = 0; k < kILP; ++k) {
        const unsigned p = base + (unsigned)(k * kBlock);
        const float px = x[p * 3u + 0u];
        const float py = x[p * 3u + 1u];
        const float pz = x[p * 3u + 2u];
        const unsigned x0 = (unsigned)floorf(px * r);
        const unsigned y0 = (unsigned)floorf(py * r);
        const unsigned z0 = (unsigned)floorf(pz * r);
        const unsigned h  = (x0 ^ (y0 * 2654435761u) ^ (z0 * 805459861u)) & kHashMask;
        const u64 e = tab[h];                      // L2-resident gather
        __builtin_nontemporal_store(e, wsl + p);   // coalesced stream
    }
}

// ---------- Pass 2: gather levels 0..2 + read ws + LDS-staged assembly ----
// Every global store here is 64 lanes x 16 B contiguous (full 64-B lines),
// so the 201 MB out stream writes each line exactly once.
__global__ __launch_bounds__(kBlock) void assemble_kernel(
    const float* __restrict__ x,
    const u64*   __restrict__ emb,
    const u64*   __restrict__ ws,
    u64x2*       __restrict__ out,   // [N*6] of 16 B  (== [N,24] f32)
    ResArr res)
{
    __shared__ u64 lds[kBlock][kLevels + 1];       // +1 u64 pad: 2-way banks max
    const unsigned t    = threadIdx.x;
    const unsigned base = blockIdx.x * (unsigned)kBlock;
    const unsigned p    = base + t;

    const float px = x[p * 3u + 0u];
    const float py = x[p * 3u + 1u];
    const float pz = x[p * 3u + 2u];

#pragma unroll
    for (int l = 0; l < kLowLevels; ++l) {         // small tables: L2 hits
        const float r = res.r[l];
        const unsigned x0 = (unsigned)floorf(px * r);
        const unsigned y0 = (unsigned)floorf(py * r);
        const unsigned z0 = (unsigned)floorf(pz * r);
        const unsigned h  = (x0 ^ (y0 * 2654435761u) ^ (z0 * 805459861u)) & kHashMask;
        lds[t][l] = emb[(size_t)l * kHashSize + h];
    }
#pragma unroll
    for (int li = 0; li < kHiLevels; ++li) {       // coalesced 512 B/instr
        lds[t][kLowLevels + li] =
            __builtin_nontemporal_load(ws + (size_t)li * kPoints + p);
    }
    __syncthreads();

    // block's out range: [base*6, base*6 + 1536) u64x2 elements, contiguous
#pragma unroll
    for (int j = 0; j < 6; ++j) {
        const unsigned el = (unsigned)(j * kBlock) + t;   // 0..1535
        const unsigned p2 = el / 6u;
        const unsigned s2 = el - p2 * 6u;
        u64x2 o;
        o.x = lds[p2][2u * s2 + 0u];
        o.y = lds[p2][2u * s2 + 1u];
        __builtin_nontemporal_store(o, out + (size_t)base * 6u + el);
    }
}

// ---------- Fallback: round-1 direct kernel (if ws too small) -------------
__global__ __launch_bounds__(kBlock) void direct_kernel(
    const float* __restrict__ x,
    const u64*   __restrict__ emb,
    u64*         __restrict__ out,
    ResArr res)
{
    unsigned tid = blockIdx.x * (unsigned)kBlock + threadIdx.x;  // n*12 + l
    unsigned n   = tid / (unsigned)kLevels;
    unsigned l   = tid - n * (unsigned)kLevels;
    float r = res.r[0];
#pragma unroll
    for (int i = 1; i < kLevels; ++i) r = (l == (unsigned)i) ? res.r[i] : r;
    float px = x[n * 3u], py = x[n * 3u + 1u], pz = x[n * 3u + 2u];
    unsigned x0 = (unsigned)floorf(px * r);
    unsigned y0 = (unsigned)floorf(py * r);
    unsigned z0 = (unsigned)floorf(pz * r);
    unsigned h  = (x0 ^ (y0 * 2654435761u) ^ (z0 * 805459861u)) & kHashMask;
    __builtin_nontemporal_store(emb[l * kHashSize + h], out + tid);
}

extern "C" void kernel_launch(void* const* d_in, const int* in_sizes, int n_in,
                              void* d_out, int out_size, void* d_ws, size_t ws_size,
                              hipStream_t stream) {
    const float* x   = (const float*)d_in[0];
    const u64*   emb = (const u64*)d_in[1];

    // Replicate the reference's float64 resolution computation exactly.
    ResArr res;
    const double growth = std::exp((std::log(512.0) - std::log(16.0)) / 11.0);
    for (int i = 0; i < kLevels; ++i)
        res.r[i] = (float)(int)(16.0 * std::pow(growth, (double)i));

    const size_t ws_needed = (size_t)kHiLevels * kPoints * sizeof(u64); // 151 MB

    if (ws_size >= ws_needed) {
        hipLaunchKernelGGL(gather_hi_kernel, dim3(kGBlocks), dim3(kBlock), 0, stream,
                           x, emb, (u64*)d_ws, res);
        hipLaunchKernelGGL(assemble_kernel, dim3(kPoints / kBlock), dim3(kBlock), 0, stream,
                           x, emb, (const u64*)d_ws, (u64x2*)d_out, res);
    } else {
        const int total = kPoints * kLevels;
        hipLaunchKernelGGL(direct_kernel, dim3(total / kBlock), dim3(kBlock), 0, stream,
                           x, emb, (u64*)d_out, res);
    }
}